// Round 2
// baseline (2956.801 us; speedup 1.0000x reference)
//
#include <hip/hip_runtime.h>
#include <hip/hip_bf16.h>

#define LDSK 136  // padded LDS row stride (elements) for transposed weight tile

typedef __bf16 bf16x8_t __attribute__((ext_vector_type(8)));
typedef float  f32x4_t  __attribute__((ext_vector_type(4)));

__device__ __forceinline__ float gelu_f(float x) {
    return 0.5f * x * (1.0f + erff(x * 0.70710678118654752440f));
}

// Stage W[128][128] fp32 (row-major, x@W) transposed into LDS as bf16:
// Wt[n][k], row stride LDSK. Also stage fp32 bias.
__device__ __forceinline__ void stage_w_bias(const float* __restrict__ W,
                                             const float* __restrict__ bvec,
                                             __bf16* Wt, float* bias_s) {
    for (int i = threadIdx.x * 8; i < 128 * 128; i += 256 * 8) {
        int k = i >> 7, n = i & 127;
        f32x4_t v0 = *(const f32x4_t*)(W + i);
        f32x4_t v1 = *(const f32x4_t*)(W + i + 4);
        #pragma unroll
        for (int j = 0; j < 4; ++j) {
            Wt[(n + j) * LDSK + k]     = (__bf16)v0[j];
            Wt[(n + 4 + j) * LDSK + k] = (__bf16)v1[j];
        }
    }
    if (threadIdx.x < 128) bias_s[threadIdx.x] = bvec[threadIdx.x];
}

// OUT[row] = (accum?OUT:0) + op( (A*ascale) @ W + bias + (ADD?ADD:0) ), op=gelu if do_gelu
__global__ __launch_bounds__(256) void k_node_gemm(
    const float* __restrict__ A, int M,
    const float* __restrict__ W, const float* __restrict__ bvec,
    const float* __restrict__ eps_elem,
    const float* __restrict__ ADD, float* __restrict__ OUT,
    int do_gelu, int accum)
{
    __shared__ __align__(16) __bf16 Wt[128 * LDSK];
    __shared__ __align__(16) float bias_s[128];
    stage_w_bias(W, bvec, Wt, bias_s);
    __syncthreads();

    int lane = threadIdx.x & 63, wave = threadIdx.x >> 6;
    int q = lane >> 4, c = lane & 15;
    int m0 = blockIdx.x * 64 + wave * 16;

    float ascale = 1.0f;
    if (eps_elem) ascale = 1.0f + *eps_elem;

    int arow = m0 + c;
    bf16x8_t afr[4];
    if (arow < M) {
        const float* ap = A + (size_t)arow * 128;
        #pragma unroll
        for (int kb = 0; kb < 4; ++kb) {
            const float* p = ap + kb * 32 + q * 8;
            f32x4_t x0 = *(const f32x4_t*)p;
            f32x4_t x1 = *(const f32x4_t*)(p + 4);
            bf16x8_t v;
            #pragma unroll
            for (int j = 0; j < 4; ++j) {
                v[j]     = (__bf16)(x0[j] * ascale);
                v[j + 4] = (__bf16)(x1[j] * ascale);
            }
            afr[kb] = v;
        }
    } else {
        #pragma unroll
        for (int kb = 0; kb < 4; ++kb) {
            bf16x8_t z;
            #pragma unroll
            for (int j = 0; j < 8; ++j) z[j] = (__bf16)0.0f;
            afr[kb] = z;
        }
    }

    #pragma unroll
    for (int nt = 0; nt < 8; ++nt) {
        f32x4_t acc = {0.f, 0.f, 0.f, 0.f};
        #pragma unroll
        for (int kb = 0; kb < 4; ++kb) {
            bf16x8_t b = *(const bf16x8_t*)&Wt[(nt * 16 + c) * LDSK + kb * 32 + q * 8];
            acc = __builtin_amdgcn_mfma_f32_16x16x32_bf16(afr[kb], b, acc, 0, 0, 0);
        }
        int col = nt * 16 + c;
        #pragma unroll
        for (int r = 0; r < 4; ++r) {
            int rowg = m0 + q * 4 + r;
            if (rowg < M) {
                size_t o = (size_t)rowg * 128 + col;
                float v = acc[r] + bias_s[col];
                if (ADD) v += ADD[o];
                if (do_gelu) v = gelu_f(v);
                if (accum) v += OUT[o];
                OUT[o] = v;
            }
        }
    }
}

// ---------- dst-sort preprocessing (counting sort, once per launch) ----------

__global__ void k_zero_i(int* __restrict__ p, int n) {
    int i = blockIdx.x * 256 + threadIdx.x;
    if (i < n) p[i] = 0;
}

__global__ void k_hist(const int* __restrict__ dst, int E, int* __restrict__ cnt) {
    int i = blockIdx.x * 256 + threadIdx.x;
    if (i < E) atomicAdd(&cnt[dst[i]], 1);
}

// single-block exclusive prefix scan: cnt[n] -> off[n]
__global__ __launch_bounds__(1024) void k_scan_excl(const int* __restrict__ cnt,
                                                    int* __restrict__ off, int n) {
    __shared__ int sm[1024];
    __shared__ int carry;
    int tid = threadIdx.x;
    if (tid == 0) carry = 0;
    __syncthreads();
    for (int base = 0; base < n; base += 1024) {
        int i = base + tid;
        int v = (i < n) ? cnt[i] : 0;
        sm[tid] = v;
        __syncthreads();
        for (int o = 1; o < 1024; o <<= 1) {
            int t = (tid >= o) ? sm[tid - o] : 0;
            __syncthreads();
            sm[tid] += t;
            __syncthreads();
        }
        if (i < n) off[i] = carry + sm[tid] - v;
        int total = sm[1023];
        __syncthreads();
        if (tid == 0) carry += total;
        __syncthreads();
    }
}

// scatter edges into dst-sorted order; also emit sorted meta (coalesced reads here,
// coalesced loads in k_edge later).
__global__ void k_scatter(const int* __restrict__ src, const int* __restrict__ dst,
                          const float* __restrict__ ew, int E,
                          int* __restrict__ off, int* __restrict__ perm,
                          int* __restrict__ sse, int* __restrict__ sde,
                          float* __restrict__ sew) {
    int e = blockIdx.x * 256 + threadIdx.x;
    if (e < E) {
        int d = dst[e];
        int p = atomicAdd(&off[d], 1);
        perm[p] = e;
        sse[p]  = src[e];
        sde[p]  = d;
        sew[p]  = ew[e];
    }
}

// ---------- fused edge kernel over dst-sorted edges ----------
// e = ea@We + be ; m = gelu(XS[src] + e) * ew ; AGG[dst] += sum over dst-run.
// MFMA operands swapped vs k_node_gemm: D = (Wt-frag) x (edge-frag) transposes
// the tile so each lane owns ONE edge x 4 consecutive features. Edges are
// dst-sorted, so a segmented shfl-scan over the 16-lane edge axis collapses
// each equal-dst run to a single head lane, which issues the only atomics.
__global__ __launch_bounds__(256) void k_edge(
    const float* __restrict__ ea,
    const int* __restrict__ perm,
    const int* __restrict__ sse, const int* __restrict__ sde,
    const float* __restrict__ sew, int E,
    const float* __restrict__ W, const float* __restrict__ bvec,
    const float* __restrict__ XS, float* __restrict__ AGG)
{
    __shared__ __align__(16) __bf16 Wt[128 * LDSK];
    __shared__ __align__(16) float bias_s[128];
    stage_w_bias(W, bvec, Wt, bias_s);
    __syncthreads();

    int lane = threadIdx.x & 63, wave = threadIdx.x >> 6;
    int q = lane >> 4, c = lane & 15;
    int m0 = blockIdx.x * 64 + wave * 16;
    int es = m0 + c;                      // sorted-order edge index for this lane

    int pe = perm[es];
    const float* ap = ea + (size_t)pe * 128;
    bf16x8_t afr[4];
    #pragma unroll
    for (int kb = 0; kb < 4; ++kb) {
        const float* p = ap + kb * 32 + q * 8;
        f32x4_t x0 = *(const f32x4_t*)p;
        f32x4_t x1 = *(const f32x4_t*)(p + 4);
        bf16x8_t v;
        #pragma unroll
        for (int j = 0; j < 4; ++j) {
            v[j]     = (__bf16)x0[j];
            v[j + 4] = (__bf16)x1[j];
        }
        afr[kb] = v;
    }

    int se   = sse[es];
    int de   = sde[es];
    float wv = sew[es];
    const float* xsp = XS + (size_t)se * 128;
    float* aggp      = AGG + (size_t)de * 128;

    // run-equality masks within the 16-lane edge group (keys are contiguous runs,
    // so key match at distance `o` implies the whole span is one segment)
    int dnb;
    dnb = __shfl(de, lane + 1); bool s1 = (c + 1 < 16) && (dnb == de);
    dnb = __shfl(de, lane + 2); bool s2 = (c + 2 < 16) && (dnb == de);
    dnb = __shfl(de, lane + 4); bool s4 = (c + 4 < 16) && (dnb == de);
    dnb = __shfl(de, lane + 8); bool s8 = (c + 8 < 16) && (dnb == de);
    int dprev = __shfl(de, lane - 1);
    bool head = (c == 0) || (dprev != de);

    #pragma unroll
    for (int nt = 0; nt < 8; ++nt) {
        f32x4_t acc = {0.f, 0.f, 0.f, 0.f};
        #pragma unroll
        for (int kb = 0; kb < 4; ++kb) {
            bf16x8_t b = *(const bf16x8_t*)&Wt[(nt * 16 + c) * LDSK + kb * 32 + q * 8];
            // swapped operands: D[feature][edge] = (ea @ W)^T tile
            acc = __builtin_amdgcn_mfma_f32_16x16x32_bf16(b, afr[kb], acc, 0, 0, 0);
        }
        int col0 = nt * 16 + q * 4;       // 4 consecutive output features, this edge
        f32x4_t xs4 = *(const f32x4_t*)(xsp + col0);
        f32x4_t b4  = *(const f32x4_t*)(bias_s + col0);
        float v0 = gelu_f(acc[0] + b4[0] + xs4[0]) * wv;
        float v1 = gelu_f(acc[1] + b4[1] + xs4[1]) * wv;
        float v2 = gelu_f(acc[2] + b4[2] + xs4[2]) * wv;
        float v3 = gelu_f(acc[3] + b4[3] + xs4[3]) * wv;

        // forward segmented inclusive scan: head lane ends with the segment sum
        float n0, n1, n2, n3;
        n0 = __shfl_down(v0, 1); n1 = __shfl_down(v1, 1);
        n2 = __shfl_down(v2, 1); n3 = __shfl_down(v3, 1);
        if (s1) { v0 += n0; v1 += n1; v2 += n2; v3 += n3; }
        n0 = __shfl_down(v0, 2); n1 = __shfl_down(v1, 2);
        n2 = __shfl_down(v2, 2); n3 = __shfl_down(v3, 2);
        if (s2) { v0 += n0; v1 += n1; v2 += n2; v3 += n3; }
        n0 = __shfl_down(v0, 4); n1 = __shfl_down(v1, 4);
        n2 = __shfl_down(v2, 4); n3 = __shfl_down(v3, 4);
        if (s4) { v0 += n0; v1 += n1; v2 += n2; v3 += n3; }
        n0 = __shfl_down(v0, 8); n1 = __shfl_down(v1, 8);
        n2 = __shfl_down(v2, 8); n3 = __shfl_down(v3, 8);
        if (s8) { v0 += n0; v1 += n1; v2 += n2; v3 += n3; }

        if (head) {
            atomicAdd(aggp + col0 + 0, v0);
            atomicAdd(aggp + col0 + 1, v1);
            atomicAdd(aggp + col0 + 2, v2);
            atomicAdd(aggp + col0 + 3, v3);
        }
    }
}

__global__ void k_copy(const float* __restrict__ in, float* __restrict__ out, int n) {
    int i = blockIdx.x * 256 + threadIdx.x;
    if (i < n) out[i] = in[i];
}

__global__ void k_zero(float* __restrict__ p, int n) {
    int i = blockIdx.x * 256 + threadIdx.x;
    if (i < n) p[i] = 0.0f;
}

__global__ void k_residual(float* __restrict__ X, const float* __restrict__ O, int n) {
    int i = blockIdx.x * 256 + threadIdx.x;
    if (i < n) X[i] += gelu_f(O[i]);
}

__global__ void k_store(const float* __restrict__ XB, const float* __restrict__ XC,
                        float* __restrict__ out, int nb, int nc) {
    int i = blockIdx.x * 256 + threadIdx.x;
    if (i < nb) out[i] = XB[i];
    else if (i < nb + nc) out[i] = XC[i - nb];
}

extern "C" void kernel_launch(void* const* d_in, const int* in_sizes, int n_in,
                              void* d_out, int out_size, void* d_ws, size_t ws_size,
                              hipStream_t stream)
{
    const float* xb_in = (const float*)d_in[0];
    const float* xc_in = (const float*)d_in[1];
    const int NB = in_sizes[0] / 128;
    const int NC = in_sizes[1] / 128;

    // edge-type order t: 0=bb 1=bc 2=cc 3=cb ; input slots: bb@2, bc@5, cc@8, cb@11
    const int slot[4] = {2, 5, 8, 11};
    const int* ei_[4]; const float *ea_[4], *ew_[4]; int E_[4];
    for (int t = 0; t < 4; ++t) {
        ei_[t] = (const int*)d_in[slot[t]];
        ea_[t] = (const float*)d_in[slot[t] + 1];
        ew_[t] = (const float*)d_in[slot[t] + 2];
        E_[t]  = in_sizes[slot[t]] / 2;
    }
    const float* Wsrc = (const float*)d_in[14];
    const float* bsrc = (const float*)d_in[15];
    const float* Wdst = (const float*)d_in[16];
    const float* bdst = (const float*)d_in[17];
    const float* epsp = (const float*)d_in[18];
    const float* Wep  = (const float*)d_in[19];
    const float* bep  = (const float*)d_in[20];
    const float* Wm1  = (const float*)d_in[21];
    const float* bm1  = (const float*)d_in[22];
    const float* Wm2  = (const float*)d_in[23];
    const float* bm2  = (const float*)d_in[24];

    // fp32 workspace layout (~105 MB): T aliases AGG (AGG fully consumed by
    // the lin_dst pass before the MLP hidden overwrites it).
    float* XB  = (float*)d_ws;                 // [NB,128] current base features
    float* XC  = XB  + (size_t)NB * 128;       // [NC,128]
    float* XS  = XC  + (size_t)NC * 128;       // [NB,128] lin_src out, then H
    float* AGG = XS  + (size_t)NB * 128;       // [NB,128] segment-sum, then MLP hidden
    float* T   = AGG;
    float* OB  = AGG + (size_t)NB * 128;       // [NB,128] conv-sum for base
    float* OC  = OB  + (size_t)NB * 128;       // [NC,128] conv-sum for cent

    // int workspace (~21 MB) appended after OC: dst-sort structures per type
    int* ip = (int*)(OC + (size_t)NC * 128);
    int *PERM[4], *SSE[4], *SDE[4], *CNT[4], *OFF[4];
    float* SEW[4];
    const int nd_[4] = {NB, NC, NC, NB};       // dst node count per type
    for (int t = 0; t < 4; ++t) {
        int E = E_[t];
        PERM[t] = ip; ip += E;
        SSE[t]  = ip; ip += E;
        SDE[t]  = ip; ip += E;
        SEW[t]  = (float*)ip; ip += E;
        CNT[t]  = ip; ip += nd_[t];
        OFF[t]  = ip; ip += nd_[t];
    }

    dim3 blk(256);
    k_copy<<<dim3((NB * 128 + 255) / 256), blk, 0, stream>>>(xb_in, XB, NB * 128);
    k_copy<<<dim3((NC * 128 + 255) / 256), blk, 0, stream>>>(xc_in, XC, NC * 128);

    // build dst-sorted edge permutations (once; reused by both layers)
    for (int t = 0; t < 4; ++t) {
        int E = E_[t], nd = nd_[t];
        const int* dstp = ei_[t] + E;
        k_zero_i<<<dim3((nd + 255) / 256), blk, 0, stream>>>(CNT[t], nd);
        k_hist<<<dim3((E + 255) / 256), blk, 0, stream>>>(dstp, E, CNT[t]);
        k_scan_excl<<<dim3(1), dim3(1024), 0, stream>>>(CNT[t], OFF[t], nd);
        k_scatter<<<dim3((E + 255) / 256), blk, 0, stream>>>(
            ei_[t], dstp, ew_[t], E, OFF[t], PERM[t], SSE[t], SDE[t], SEW[t]);
    }

    const int tlist[4] = {0, 3, 1, 2};  // bb, cb -> OB ; bc, cc -> OC
    for (int l = 0; l < 2; ++l) {
        for (int bi = 0; bi < 4; ++bi) {
            int t = tlist[bi];
            const float* srcx = (t == 0 || t == 1) ? XB : XC;
            int ns            = (t == 0 || t == 1) ? NB : NC;
            const float* dstx = (t == 0 || t == 3) ? XB : XC;
            int nd            = (t == 0 || t == 3) ? NB : NC;
            float* outp       = (t == 0 || t == 3) ? OB : OC;
            int accum         = (bi == 1 || bi == 3);
            size_t pi = (size_t)(l * 4 + t);

            // xs = x_src @ Wsrc + bsrc
            k_node_gemm<<<dim3((ns + 63) / 64), blk, 0, stream>>>(
                srcx, ns, Wsrc + pi * 16384, bsrc + pi * 128,
                nullptr, nullptr, XS, 0, 0);
            // agg = 0
            int nz = nd * 128;
            k_zero<<<dim3((nz + 255) / 256), blk, 0, stream>>>(AGG, nz);
            // agg += scatter(gelu(xs[src] + ea@We + be) * ew), dst-sorted + segmented
            int E = E_[t];
            k_edge<<<dim3(E / 64), blk, 0, stream>>>(
                ea_[t], PERM[t], SSE[t], SDE[t], SEW[t], E,
                Wep + pi * 16384, bep + pi * 128, XS, AGG);
            // H = agg + ((1+eps)*x_dst) @ Wd + bd   (H overwrites XS)
            k_node_gemm<<<dim3((nd + 63) / 64), blk, 0, stream>>>(
                dstx, nd, Wdst + pi * 16384, bdst + pi * 128,
                epsp + pi, AGG, XS, 0, 0);
            // T = gelu(H @ W1 + b1)   (T aliases AGG, AGG already consumed)
            k_node_gemm<<<dim3((nd + 63) / 64), blk, 0, stream>>>(
                XS, nd, Wm1 + pi * 16384, bm1 + pi * 128,
                nullptr, nullptr, T, 1, 0);
            // out (+)= T @ W2 + b2
            k_node_gemm<<<dim3((nd + 63) / 64), blk, 0, stream>>>(
                T, nd, Wm2 + pi * 16384, bm2 + pi * 128,
                nullptr, nullptr, outp, 0, accum);
        }
        k_residual<<<dim3((NB * 128 + 255) / 256), blk, 0, stream>>>(XB, OB, NB * 128);
        k_residual<<<dim3((NC * 128 + 255) / 256), blk, 0, stream>>>(XC, OC, NC * 128);
    }
    k_store<<<dim3((out_size + 255) / 256), blk, 0, stream>>>(
        XB, XC, (float*)d_out, NB * 128, NC * 128);
}